// Round 1
// baseline (296.071 us; speedup 1.0000x reference)
//
#include <hip/hip_runtime.h>

typedef _Float16 f16;
typedef _Float16 f16x2 __attribute__((ext_vector_type(2)));
typedef _Float16 f16x8 __attribute__((ext_vector_type(8)));
typedef float f32x4 __attribute__((ext_vector_type(4)));

#define I_DIM 320
#define J_DIM 320
#define C_DIM 128
#define H_DIM 4
#define DH 32
#define NROWS (I_DIM * J_DIM)   // 102400

// ---------------- K1: LayerNorm (f32 -> f16) ----------------
__global__ __launch_bounds__(256) void ln_kernel(const float* __restrict__ z,
                                                 const float* __restrict__ scale,
                                                 const float* __restrict__ bias,
                                                 f16* __restrict__ zn) {
    int wave = threadIdx.x >> 6;
    int lane = threadIdx.x & 63;
    int row = blockIdx.x * 4 + wave;
    const float* zr = z + (size_t)row * C_DIM;
    float2 x = *(const float2*)(zr + lane * 2);
    float s = x.x + x.y;
    float sq = x.x * x.x + x.y * x.y;
    #pragma unroll
    for (int o = 32; o; o >>= 1) {
        s  += __shfl_xor(s, o);
        sq += __shfl_xor(sq, o);
    }
    float mu = s * (1.0f / 128.0f);
    float var = sq * (1.0f / 128.0f) - mu * mu;
    float rs = rsqrtf(var + 1e-5f);
    int c0 = lane * 2;
    float y0 = (x.x - mu) * rs * scale[c0] + bias[c0];
    float y1 = (x.y - mu) * rs * scale[c0 + 1] + bias[c0 + 1];
    f16x2 o2 = {(f16)y0, (f16)y1};
    *(f16x2*)(zn + (size_t)row * C_DIM + c0) = o2;
}

// ---------------- K2: fused QKVG projection (MFMA f16) ----------------
// grid: NROWS/64 blocks, 256 threads. Wave w computes zn@W_w for its 64-row tile.
__global__ __launch_bounds__(256) void proj_kernel(const f16* __restrict__ zn,
                                                   const float* __restrict__ Wq,
                                                   const float* __restrict__ Wk,
                                                   const float* __restrict__ Wv,
                                                   const float* __restrict__ Wg,
                                                   const float* __restrict__ bg,
                                                   f16* __restrict__ q, f16* __restrict__ k,
                                                   f16* __restrict__ v, f16* __restrict__ g) {
    int wave = threadIdx.x >> 6;
    int lane = threadIdx.x & 63;
    int gq = lane >> 4, r16 = lane & 15;
    int row0 = blockIdx.x * 64;

    const float* W = (wave == 0) ? Wq : (wave == 1) ? Wk : (wave == 2) ? Wv : Wg;

    f32x4 acc[4][8] = {};
    #pragma unroll
    for (int ks = 0; ks < 4; ++ks) {
        f16x8 a[4];
        #pragma unroll
        for (int m = 0; m < 4; ++m)
            a[m] = *(const f16x8*)(zn + (size_t)(row0 + m * 16 + r16) * C_DIM + ks * 32 + gq * 8);
        #pragma unroll
        for (int n = 0; n < 8; ++n) {
            const float* wp = W + (size_t)(ks * 32 + gq * 8) * 128 + n * 16 + r16;
            f16x8 b;
            #pragma unroll
            for (int j = 0; j < 8; ++j) b[j] = (f16)wp[(size_t)j * 128];
            #pragma unroll
            for (int m = 0; m < 4; ++m)
                acc[m][n] = __builtin_amdgcn_mfma_f32_16x16x32_f16(a[m], b, acc[m][n], 0, 0, 0);
        }
    }

    f16* outp = (wave == 0) ? q : (wave == 1) ? k : (wave == 2) ? v : g;
    #pragma unroll
    for (int m = 0; m < 4; ++m) {
        #pragma unroll
        for (int n = 0; n < 8; ++n) {
            int col = n * 16 + r16;
            #pragma unroll
            for (int rr = 0; rr < 4; ++rr) {
                int row = row0 + m * 16 + gq * 4 + rr;
                float val = acc[m][n][rr];
                if (wave == 3) val = 1.0f / (1.0f + __expf(-(val + bg[col])));
                outp[(size_t)row * C_DIM + col] = (f16)val;
            }
        }
    }
}

// ---------------- K3: attention per (i,h) ----------------
// grid 1280 = i*4+h, 256 threads (4 waves), each wave 5 qtiles of 16 queries.
__global__ __launch_bounds__(256) void attn_kernel(const f16* __restrict__ q,
                                                   const f16* __restrict__ k,
                                                   const f16* __restrict__ v,
                                                   const f16* __restrict__ g,
                                                   const int* __restrict__ z_mask,
                                                   f16* __restrict__ gwa) {
    __shared__ f16 Ksh[320][40];      // padded rows: 80B stride -> 2-way banks only
    __shared__ f16 Vt[32][328];       // V transposed [dh][key], padded
    __shared__ float mb[320];
    __shared__ f16 Psh[4][2][16][40]; // per-wave, double-buffered P chunk

    int h = blockIdx.x & 3;
    int i = blockIdx.x >> 2;
    size_t base = (size_t)i * (J_DIM * C_DIM) + h * DH;

    // stage K and V^T
    for (int t = threadIdx.x; t < 320 * 4; t += 256) {
        int row = t >> 2, c8 = (t & 3) * 8;
        f16x8 kv = *(const f16x8*)(k + base + (size_t)row * C_DIM + c8);
        *(f16x8*)(&Ksh[row][c8]) = kv;
        f16x8 vv = *(const f16x8*)(v + base + (size_t)row * C_DIM + c8);
        #pragma unroll
        for (int j = 0; j < 8; ++j) Vt[c8 + j][row] = vv[j];
    }
    for (int t = threadIdx.x; t < 320; t += 256)
        mb[t] = 1e9f * ((float)z_mask[i * J_DIM + t] - 1.0f);
    __syncthreads();

    int wave = threadIdx.x >> 6;
    int lane = threadIdx.x & 63;
    int gq = lane >> 4, r16 = lane & 15;

    for (int qt = wave; qt < 20; qt += 4) {
        f16x8 qa = *(const f16x8*)(q + base + (size_t)(qt * 16 + r16) * C_DIM + gq * 8);
        f32x4 zero = {};
        f32x4 lg[20];
        #pragma unroll
        for (int kt = 0; kt < 20; ++kt) {
            f16x8 kb = *(const f16x8*)(&Ksh[kt * 16 + r16][gq * 8]);
            lg[kt] = __builtin_amdgcn_mfma_f32_16x16x32_f16(qa, kb, zero, 0, 0, 0);
        }
        // softmax over 320 keys, rows q = qt*16 + gq*4 + r
        float rinv[4];
        #pragma unroll
        for (int r = 0; r < 4; ++r) {
            float mx = -3e38f;
            #pragma unroll
            for (int kt = 0; kt < 20; ++kt) {
                float t = lg[kt][r] + mb[kt * 16 + r16];
                lg[kt][r] = t;
                mx = fmaxf(mx, t);
            }
            #pragma unroll
            for (int o = 1; o < 16; o <<= 1) mx = fmaxf(mx, __shfl_xor(mx, o));
            float s = 0.0f;
            #pragma unroll
            for (int kt = 0; kt < 20; ++kt) {
                float e = __expf(lg[kt][r] - mx);
                lg[kt][r] = e;
                s += e;
            }
            #pragma unroll
            for (int o = 1; o < 16; o <<= 1) s += __shfl_xor(s, o);
            rinv[r] = 1.0f / s;
        }
        // PV via LDS round-trip for P (layout-agnostic)
        f32x4 wa[2] = {};
        #pragma unroll
        for (int kc = 0; kc < 10; ++kc) {
            int buf = kc & 1;
            #pragma unroll
            for (int t = 0; t < 2; ++t) {
                int kt = kc * 2 + t;
                #pragma unroll
                for (int r = 0; r < 4; ++r)
                    Psh[wave][buf][gq * 4 + r][t * 16 + r16] = (f16)(lg[kt][r] * rinv[r]);
            }
            asm volatile("s_waitcnt lgkmcnt(0)" ::: "memory");
            f16x8 pa = *(const f16x8*)(&Psh[wave][buf][r16][gq * 8]);
            #pragma unroll
            for (int n = 0; n < 2; ++n) {
                f16x8 vb = *(const f16x8*)(&Vt[n * 16 + r16][kc * 32 + gq * 8]);
                wa[n] = __builtin_amdgcn_mfma_f32_16x16x32_f16(pa, vb, wa[n], 0, 0, 0);
            }
        }
        // gate + store
        #pragma unroll
        for (int n = 0; n < 2; ++n) {
            #pragma unroll
            for (int r = 0; r < 4; ++r) {
                int jq = qt * 16 + gq * 4 + r;
                int dh = n * 16 + r16;
                size_t idx = base + (size_t)jq * C_DIM + dh;
                float gv = (float)g[idx];
                gwa[idx] = (f16)(gv * wa[n][r]);
            }
        }
    }
}

// ---------------- K4: output projection + bias + query mask ----------------
// grid 400 blocks, wave w owns 64-row subtile of the block's 256 rows.
__global__ __launch_bounds__(256) void out_kernel(const f16* __restrict__ gwa,
                                                  const float* __restrict__ Wo,
                                                  const float* __restrict__ bo,
                                                  const int* __restrict__ z_mask,
                                                  float* __restrict__ out) {
    int wave = threadIdx.x >> 6;
    int lane = threadIdx.x & 63;
    int gq = lane >> 4, r16 = lane & 15;
    int row0 = blockIdx.x * 256 + wave * 64;

    f32x4 acc[4][8] = {};
    #pragma unroll
    for (int ks = 0; ks < 4; ++ks) {
        f16x8 a[4];
        #pragma unroll
        for (int m = 0; m < 4; ++m)
            a[m] = *(const f16x8*)(gwa + (size_t)(row0 + m * 16 + r16) * C_DIM + ks * 32 + gq * 8);
        #pragma unroll
        for (int n = 0; n < 8; ++n) {
            const float* wp = Wo + (size_t)(ks * 32 + gq * 8) * 128 + n * 16 + r16;
            f16x8 b;
            #pragma unroll
            for (int j = 0; j < 8; ++j) b[j] = (f16)wp[(size_t)j * 128];
            #pragma unroll
            for (int m = 0; m < 4; ++m)
                acc[m][n] = __builtin_amdgcn_mfma_f32_16x16x32_f16(a[m], b, acc[m][n], 0, 0, 0);
        }
    }
    #pragma unroll
    for (int m = 0; m < 4; ++m) {
        #pragma unroll
        for (int rr = 0; rr < 4; ++rr) {
            int row = row0 + m * 16 + gq * 4 + rr;
            float mk = (float)z_mask[row];
            #pragma unroll
            for (int n = 0; n < 8; ++n) {
                int col = n * 16 + r16;
                out[(size_t)row * C_DIM + col] = (acc[m][n][rr] + bo[col]) * mk;
            }
        }
    }
}

extern "C" void kernel_launch(void* const* d_in, const int* in_sizes, int n_in,
                              void* d_out, int out_size, void* d_ws, size_t ws_size,
                              hipStream_t stream) {
    const float* z       = (const float*)d_in[0];
    const int*   z_mask  = (const int*)d_in[1];
    const float* ln_scale= (const float*)d_in[2];
    const float* ln_bias = (const float*)d_in[3];
    const float* Wq      = (const float*)d_in[4];
    const float* Wk      = (const float*)d_in[5];
    const float* Wv      = (const float*)d_in[6];
    const float* Wg      = (const float*)d_in[7];
    const float* bg      = (const float*)d_in[8];
    const float* Wo      = (const float*)d_in[9];
    const float* bo      = (const float*)d_in[10];
    float* out = (float*)d_out;

    char* ws = (char*)d_ws;
    const size_t SZ = (size_t)NROWS * C_DIM * sizeof(f16);  // 26.2 MB
    f16* zn  = (f16*)(ws);
    f16* q   = (f16*)(ws + 1 * SZ);
    f16* k   = (f16*)(ws + 2 * SZ);
    f16* v   = (f16*)(ws + 3 * SZ);
    f16* g   = (f16*)(ws + 4 * SZ);
    f16* gwa = zn;  // zn dead after proj_kernel

    ln_kernel  <<<NROWS / 4, 256, 0, stream>>>(z, ln_scale, ln_bias, zn);
    proj_kernel<<<NROWS / 64, 256, 0, stream>>>(zn, Wq, Wk, Wv, Wg, bg, q, k, v, g);
    attn_kernel<<<I_DIM * H_DIM, 256, 0, stream>>>(q, k, v, g, z_mask, gwa);
    out_kernel <<<NROWS / 256, 256, 0, stream>>>(gwa, Wo, bo, z_mask, out);
}